// Round 4
// baseline (33.077 us; speedup 1.0000x reference)
//
#include <hip/hip_runtime.h>
#include <hip/hip_bf16.h>
#include <math.h>

// Problem constants (from reference)
#define BB 256
#define NN 16
#define MM 128
#define VV 512
#define KK 8
#define NP1 17   // N+1

typedef float f32x4 __attribute__((ext_vector_type(4)));   // native vector for NT builtins

// ---------------------------------------------------------------------------
// Fused kernel: ONE block per batch, 1024 threads (16 waves).
//
// Step 1: waves 0..7 each handle k = wave:
//   idx  = gumbel-argmax over the 17 masked logits (0 => PAD slice)
//   olen = 1 + last row m of decodings[b,idx-1] whose argmax != 0,
//          scanned backward (expected ~1 row read for random data)
// Step 2: threads 0..127 build output-row -> source-row map (K-segment
//   prefix with clipping at M) in shared.
// Step 3: all 16 waves gather 128 rows x 512 floats with NT loads/stores.
// ---------------------------------------------------------------------------
__global__ __launch_bounds__(1024) void fused_place(
        const float* __restrict__ decodings,   // [B,N,M,V]
        const float* __restrict__ dec_logits,  // [B,K,N+1]
        const float* __restrict__ noise,       // [B,K,N+1]
        const int*   __restrict__ ttypes,      // [B]
        const int*   __restrict__ spans,       // [B]
        float* __restrict__ out)               // [B,M,V]
{
    const int b    = blockIdx.x;
    const int tid  = threadIdx.x;
    const int wave = tid >> 6;                // 0..15
    const int lane = tid & 63;

    __shared__ int s_idx[KK];
    __shared__ int s_olen[KK];
    __shared__ int s_src[MM];

    // ---- Step 1: idx + olen, one k per wave (waves 0..7) ----
    if (wave < KK) {
        const int k = wave;
        int idx;
        if (ttypes[b] == 20) {
            idx = (k == 0) ? 1 : 0;   // start_template
        } else {
            const int span = spans[b];
            float score = -INFINITY;
            int   bi    = 1000;
            if (lane < NP1) {
                const int base = (b * KK + k) * NP1 + lane;
                float logit = dec_logits[base];
                float u     = noise[base];
                float g     = -logf(-logf(u));            // gumbel noise
                float m     = (lane <= span) ? logit : -1e9f;
                score = m + g;
                bi    = lane;
            }
            // wave argmax, first-index tie-break (matches jnp.argmax)
            for (int off = 32; off; off >>= 1) {
                float s2 = __shfl_down(score, off);
                int   b2 = __shfl_down(bi, off);
                if (s2 > score || (s2 == score && b2 < bi)) { score = s2; bi = b2; }
            }
            idx = __shfl(bi, 0);
        }

        int olen = 0;
        if (idx > 0) {
            const float* base = decodings + (((size_t)b * NN + (idx - 1)) * MM) * (size_t)VV;
            for (int m = MM - 1; m >= 0; --m) {
                const f32x4* row = (const f32x4*)(base + (size_t)m * VV);
                f32x4 a = row[lane];        // v = 4*lane .. 4*lane+3
                f32x4 c = row[64 + lane];   // v = 256+4*lane .. +3
                float r0 = __shfl(a.x, 0);  // row[0]
                float mx = fmaxf(fmaxf(a.y, a.z), a.w);
                if (lane != 0) mx = fmaxf(mx, a.x);      // exclude v=0 only on lane 0
                mx = fmaxf(mx, fmaxf(fmaxf(c.x, c.y), fmaxf(c.z, c.w)));
                for (int off = 32; off; off >>= 1) mx = fmaxf(mx, __shfl_xor(mx, off));
                if (mx > r0) { olen = m + 1; break; }    // argmax(row) != 0
            }
        }

        if (lane == 0) {
            s_idx[k]  = idx;
            s_olen[k] = olen;
        }
    }
    __syncthreads();

    // ---- Step 2: build row -> source map for all 128 rows ----
    if (tid < MM) {
        const int m_out = tid;
        int start = 0;
        int src   = -1;
        #pragma unroll
        for (int kk = 0; kk < KK; ++kk) {
            int id = s_idx[kk];
            int ol = min(s_olen[kk], MM - start);    // clip to remaining space
            if (m_out >= start && m_out < start + ol)
                src = (id - 1) * MM + (m_out - start);
            start += ol;
        }
        s_src[tid] = src;
    }
    __syncthreads();

    // ---- Step 3: gather 128 rows x 512 floats (16384 float4, 1024 threads) ----
    const f32x4* dec4 = (const f32x4*)(decodings + (size_t)b * NN * MM * VV);
    f32x4*       out4 = (f32x4*)(out + (size_t)b * MM * (size_t)VV);

    #pragma unroll
    for (int i = 0; i < 16; ++i) {
        int flat    = i * 1024 + tid;  // float4 index within the 128 rows
        int m_local = flat >> 7;       // 128 float4 per row
        int v4      = flat & 127;
        int s       = s_src[m_local];
        f32x4 val;
        if (s >= 0) val = __builtin_nontemporal_load(&dec4[(size_t)s * 128 + v4]);
        else        val = (f32x4){0.f, 0.f, 0.f, 0.f};
        __builtin_nontemporal_store(val, &out4[flat]);
    }
}

extern "C" void kernel_launch(void* const* d_in, const int* in_sizes, int n_in,
                              void* d_out, int out_size, void* d_ws, size_t ws_size,
                              hipStream_t stream) {
    const float* decodings  = (const float*)d_in[0];
    const float* dec_logits = (const float*)d_in[1];
    const float* noise      = (const float*)d_in[2];
    const int*   ttypes     = (const int*)d_in[3];
    const int*   spans      = (const int*)d_in[4];
    float* out = (float*)d_out;

    // 1 block per batch -> 256 blocks of 1024 threads
    fused_place<<<BB, 1024, 0, stream>>>(decodings, dec_logits, noise,
                                         ttypes, spans, out);
}

// Round 5
// 31.033 us; speedup vs baseline: 1.0659x; 1.0659x over previous
//
#include <hip/hip_runtime.h>
#include <hip/hip_bf16.h>
#include <math.h>

// Problem constants (from reference)
#define BB 256
#define NN 16
#define MM 128
#define VV 512
#define KK 8
#define NP1 17   // N+1

typedef float f32x4 __attribute__((ext_vector_type(4)));   // native vector for NT builtins

// ---------------------------------------------------------------------------
// Fused kernel: 2 blocks per batch, 512 threads (8 waves) each.
//
// Step 1 (per block, redundant across the 2 blocks of a batch):
//   wave w computes, for k = w:
//     idx  = gumbel-argmax over the 17 masked logits (0 => PAD slice)
//     olen = 1 + last row m of decodings[b,idx-1] whose argmax != 0,
//            scanned backward (expected ~1 row read for random data)
// Step 2: threads 0..63 build the output-row -> source-row map (K-segment
//   prefix with clipping at M) for this block's 64 rows, in shared.
// Step 3: float4 gather (non-temporal loads) / zero fill; regular stores.
// ---------------------------------------------------------------------------
__global__ __launch_bounds__(512) void fused_place(
        const float* __restrict__ decodings,   // [B,N,M,V]
        const float* __restrict__ dec_logits,  // [B,K,N+1]
        const float* __restrict__ noise,       // [B,K,N+1]
        const int*   __restrict__ ttypes,      // [B]
        const int*   __restrict__ spans,       // [B]
        float* __restrict__ out)               // [B,M,V]
{
    const int b    = blockIdx.x >> 1;
    const int part = blockIdx.x & 1;          // which 64-row half of out[b]
    const int tid  = threadIdx.x;
    const int wave = tid >> 6;                // 0..7 == k
    const int lane = tid & 63;
    const int k    = wave;

    __shared__ int s_idx[KK];
    __shared__ int s_olen[KK];
    __shared__ int s_src[64];

    // ---- Step 1: idx + olen for k = wave ----
    int idx;
    if (ttypes[b] == 20) {
        idx = (k == 0) ? 1 : 0;   // start_template: row0 -> one-hot(1), rest -> one-hot(0)
    } else {
        const int span = spans[b];
        float score = -INFINITY;
        int   bi    = 1000;
        if (lane < NP1) {
            const int base = (b * KK + k) * NP1 + lane;
            float logit = dec_logits[base];
            float u     = noise[base];
            float g     = -logf(-logf(u));            // gumbel noise
            float m     = (lane <= span) ? logit : -1e9f;
            score = m + g;
            bi    = lane;
        }
        // wave argmax, first-index tie-break (matches jnp.argmax)
        for (int off = 32; off; off >>= 1) {
            float s2 = __shfl_down(score, off);
            int   b2 = __shfl_down(bi, off);
            if (s2 > score || (s2 == score && b2 < bi)) { score = s2; bi = b2; }
        }
        idx = __shfl(bi, 0);
    }

    int olen = 0;
    if (idx > 0) {
        const float* base = decodings + (((size_t)b * NN + (idx - 1)) * MM) * (size_t)VV;
        for (int m = MM - 1; m >= 0; --m) {
            const f32x4* row = (const f32x4*)(base + (size_t)m * VV);
            f32x4 a = row[lane];        // v = 4*lane .. 4*lane+3
            f32x4 c = row[64 + lane];   // v = 256+4*lane .. +3
            float r0 = __shfl(a.x, 0);  // row[0]
            float mx = fmaxf(fmaxf(a.y, a.z), a.w);
            if (lane != 0) mx = fmaxf(mx, a.x);      // exclude v=0 only on lane 0
            mx = fmaxf(mx, fmaxf(fmaxf(c.x, c.y), fmaxf(c.z, c.w)));
            for (int off = 32; off; off >>= 1) mx = fmaxf(mx, __shfl_xor(mx, off));
            if (mx > r0) { olen = m + 1; break; }    // argmax(row) != 0
        }
    }

    if (lane == 0) {
        s_idx[k]  = idx;
        s_olen[k] = olen;
    }
    __syncthreads();

    // ---- Step 2: build row -> source map for our 64 rows ----
    if (tid < 64) {
        const int m_out = part * 64 + tid;
        int start = 0;
        int src   = -1;
        #pragma unroll
        for (int kk = 0; kk < KK; ++kk) {
            int id = s_idx[kk];
            int ol = min(s_olen[kk], MM - start);    // clip to remaining space
            if (m_out >= start && m_out < start + ol)
                src = (id - 1) * MM + (m_out - start);
            start += ol;
        }
        s_src[tid] = src;
    }
    __syncthreads();

    // ---- Step 3: gather 64 rows x 512 floats (8192 float4, 512 threads) ----
    const f32x4* dec4 = (const f32x4*)(decodings + (size_t)b * NN * MM * VV);
    f32x4*       out4 = (f32x4*)(out + ((size_t)b * MM + part * 64) * (size_t)VV);

    #pragma unroll
    for (int i = 0; i < 16; ++i) {
        int flat    = i * 512 + tid;   // float4 index within our 64 rows
        int m_local = flat >> 7;       // 128 float4 per row
        int v4      = flat & 127;
        int s       = s_src[m_local];
        f32x4 val;
        if (s >= 0) val = __builtin_nontemporal_load(&dec4[(size_t)s * 128 + v4]);
        else        val = (f32x4){0.f, 0.f, 0.f, 0.f};
        out4[flat] = val;
    }
}

extern "C" void kernel_launch(void* const* d_in, const int* in_sizes, int n_in,
                              void* d_out, int out_size, void* d_ws, size_t ws_size,
                              hipStream_t stream) {
    const float* decodings  = (const float*)d_in[0];
    const float* dec_logits = (const float*)d_in[1];
    const float* noise      = (const float*)d_in[2];
    const int*   ttypes     = (const int*)d_in[3];
    const int*   spans      = (const int*)d_in[4];
    float* out = (float*)d_out;

    // 2 blocks per batch -> 512 blocks of 512 threads
    fused_place<<<BB * 2, 512, 0, stream>>>(decodings, dec_logits, noise,
                                            ttypes, spans, out);
}

// Round 6
// 27.572 us; speedup vs baseline: 1.1997x; 1.1255x over previous
//
#include <hip/hip_runtime.h>
#include <hip/hip_bf16.h>
#include <math.h>

// Problem constants (from reference)
#define BB 256
#define NN 16
#define MM 128
#define VV 512
#define KK 8
#define NP1 17   // N+1

typedef float f32x4 __attribute__((ext_vector_type(4)));

// ---------------------------------------------------------------------------
// Fused kernel: 2 blocks per batch, 512 threads (8 waves) each.
// Block index remapped so the two blocks of a batch land on the SAME XCD
// (dispatch round-robins i%8): x and x+8 share b, so duplicated probe reads
// hit the partner's L2 lines instead of re-fetching HBM cross-XCD.
//
// Step 1 (per block, redundant across the 2 blocks of a batch):
//   wave w computes, for k = w:
//     idx  = gumbel-argmax over the 17 masked logits (0 => PAD slice)
//     olen = 1 + last row m of decodings[b,idx-1] whose argmax != 0,
//            scanned backward (expected ~1 row read for random data)
// Step 2: threads 0..63 build the output-row -> source-row map (K-segment
//   prefix with clipping at M) for this block's 64 rows, in shared.
// Step 3: grouped float4 gather (4 loads in flight, then 4 stores).
// ---------------------------------------------------------------------------
__global__ __launch_bounds__(512) void fused_place(
        const float* __restrict__ decodings,   // [B,N,M,V]
        const float* __restrict__ dec_logits,  // [B,K,N+1]
        const float* __restrict__ noise,       // [B,K,N+1]
        const int*   __restrict__ ttypes,      // [B]
        const int*   __restrict__ spans,       // [B]
        float* __restrict__ out)               // [B,M,V]
{
    const int x    = blockIdx.x;
    const int b    = (x >> 4) * 8 + (x & 7);  // batch
    const int part = (x >> 3) & 1;            // which 64-row half of out[b]
    const int tid  = threadIdx.x;
    const int wave = tid >> 6;                // 0..7 == k
    const int lane = tid & 63;
    const int k    = wave;

    __shared__ int s_idx[KK];
    __shared__ int s_olen[KK];
    __shared__ int s_src[64];

    // ---- Step 1: idx + olen for k = wave ----
    int idx;
    if (ttypes[b] == 20) {
        idx = (k == 0) ? 1 : 0;   // start_template: row0 -> one-hot(1), rest -> one-hot(0)
    } else {
        const int span = spans[b];
        float score = -INFINITY;
        int   bi    = 1000;
        if (lane < NP1) {
            const int base = (b * KK + k) * NP1 + lane;
            float logit = dec_logits[base];
            float u     = noise[base];
            float g     = -logf(-logf(u));            // gumbel noise
            float m     = (lane <= span) ? logit : -1e9f;
            score = m + g;
            bi    = lane;
        }
        // wave argmax, first-index tie-break (matches jnp.argmax)
        for (int off = 32; off; off >>= 1) {
            float s2 = __shfl_down(score, off);
            int   b2 = __shfl_down(bi, off);
            if (s2 > score || (s2 == score && b2 < bi)) { score = s2; bi = b2; }
        }
        idx = __shfl(bi, 0);
    }

    int olen = 0;
    if (idx > 0) {
        const float* base = decodings + (((size_t)b * NN + (idx - 1)) * MM) * (size_t)VV;
        for (int m = MM - 1; m >= 0; --m) {
            const f32x4* row = (const f32x4*)(base + (size_t)m * VV);
            f32x4 a = row[lane];        // v = 4*lane .. 4*lane+3
            f32x4 c = row[64 + lane];   // v = 256+4*lane .. +3
            float r0 = __shfl(a.x, 0);  // row[0]
            float mx = fmaxf(fmaxf(a.y, a.z), a.w);
            if (lane != 0) mx = fmaxf(mx, a.x);      // exclude v=0 only on lane 0
            mx = fmaxf(mx, fmaxf(fmaxf(c.x, c.y), fmaxf(c.z, c.w)));
            for (int off = 32; off; off >>= 1) mx = fmaxf(mx, __shfl_xor(mx, off));
            if (mx > r0) { olen = m + 1; break; }    // argmax(row) != 0
        }
    }

    if (lane == 0) {
        s_idx[k]  = idx;
        s_olen[k] = olen;
    }
    __syncthreads();

    // ---- Step 2: build row -> source map for our 64 rows ----
    if (tid < 64) {
        const int m_out = part * 64 + tid;
        int start = 0;
        int src   = -1;
        #pragma unroll
        for (int kk = 0; kk < KK; ++kk) {
            int id = s_idx[kk];
            int ol = min(s_olen[kk], MM - start);    // clip to remaining space
            if (m_out >= start && m_out < start + ol)
                src = (id - 1) * MM + (m_out - start);
            start += ol;
        }
        s_src[tid] = src;
    }
    __syncthreads();

    // ---- Step 3: gather 64 rows x 512 floats (8192 float4, 512 threads) ----
    // Grouped: 4 loads issued back-to-back, then 4 stores -> deeper vmcnt pipe.
    const f32x4* dec4 = (const f32x4*)(decodings + (size_t)b * NN * MM * VV);
    f32x4*       out4 = (f32x4*)(out + ((size_t)b * MM + part * 64) * (size_t)VV);

    #pragma unroll
    for (int g = 0; g < 4; ++g) {
        f32x4 v0, v1, v2, v3;
        {
            int flat = (g * 4 + 0) * 512 + tid;
            int s = s_src[flat >> 7];
            v0 = (s >= 0) ? dec4[(size_t)s * 128 + (flat & 127)] : (f32x4){0.f,0.f,0.f,0.f};
        }
        {
            int flat = (g * 4 + 1) * 512 + tid;
            int s = s_src[flat >> 7];
            v1 = (s >= 0) ? dec4[(size_t)s * 128 + (flat & 127)] : (f32x4){0.f,0.f,0.f,0.f};
        }
        {
            int flat = (g * 4 + 2) * 512 + tid;
            int s = s_src[flat >> 7];
            v2 = (s >= 0) ? dec4[(size_t)s * 128 + (flat & 127)] : (f32x4){0.f,0.f,0.f,0.f};
        }
        {
            int flat = (g * 4 + 3) * 512 + tid;
            int s = s_src[flat >> 7];
            v3 = (s >= 0) ? dec4[(size_t)s * 128 + (flat & 127)] : (f32x4){0.f,0.f,0.f,0.f};
        }
        out4[(g * 4 + 0) * 512 + tid] = v0;
        out4[(g * 4 + 1) * 512 + tid] = v1;
        out4[(g * 4 + 2) * 512 + tid] = v2;
        out4[(g * 4 + 3) * 512 + tid] = v3;
    }
}

extern "C" void kernel_launch(void* const* d_in, const int* in_sizes, int n_in,
                              void* d_out, int out_size, void* d_ws, size_t ws_size,
                              hipStream_t stream) {
    const float* decodings  = (const float*)d_in[0];
    const float* dec_logits = (const float*)d_in[1];
    const float* noise      = (const float*)d_in[2];
    const int*   ttypes     = (const int*)d_in[3];
    const int*   spans      = (const int*)d_in[4];
    float* out = (float*)d_out;

    // 2 blocks per batch -> 512 blocks of 512 threads
    fused_place<<<BB * 2, 512, 0, stream>>>(decodings, dec_logits, noise,
                                            ttypes, spans, out);
}

// Round 7
// 27.431 us; speedup vs baseline: 1.2058x; 1.0051x over previous
//
#include <hip/hip_runtime.h>
#include <hip/hip_bf16.h>
#include <math.h>

// Problem constants (from reference)
#define BB 256
#define NN 16
#define MM 128
#define VV 512
#define KK 8
#define NP1 17   // N+1

typedef float f32x4 __attribute__((ext_vector_type(4)));

// ---------------------------------------------------------------------------
// Fused kernel: 2 blocks per batch, 512 threads (8 waves) each.
// Block index remapped so the two blocks of a batch land on the SAME XCD
// (dispatch round-robins i%8): x and x+8 share b, so duplicated probe reads
// hit the partner's L2 lines instead of re-fetching HBM cross-XCD.
//
// Step 1 (per block, redundant across the 2 blocks of a batch):
//   wave w computes, for k = w:
//     idx  = gumbel-argmax over the 17 masked logits (0 => PAD slice)
//     olen = 1 + last row m of decodings[b,idx-1] whose argmax != 0,
//            scanned backward (expected ~1 row read for random data)
// Step 2: threads 0..63 build the output-row -> source-row map (K-segment
//   prefix with clipping at M) for this block's 64 rows, in shared.
// Step 3: 16-deep pipelined float4 gather: issue ALL 16 loads, then 16 stores
//   (maximize loads-in-flight; ~900cy HBM latency needs deep MLP).
// ---------------------------------------------------------------------------
__global__ __launch_bounds__(512) void fused_place(
        const float* __restrict__ decodings,   // [B,N,M,V]
        const float* __restrict__ dec_logits,  // [B,K,N+1]
        const float* __restrict__ noise,       // [B,K,N+1]
        const int*   __restrict__ ttypes,      // [B]
        const int*   __restrict__ spans,       // [B]
        float* __restrict__ out)               // [B,M,V]
{
    const int x    = blockIdx.x;
    const int b    = (x >> 4) * 8 + (x & 7);  // batch
    const int part = (x >> 3) & 1;            // which 64-row half of out[b]
    const int tid  = threadIdx.x;
    const int wave = tid >> 6;                // 0..7 == k
    const int lane = tid & 63;
    const int k    = wave;

    __shared__ int s_idx[KK];
    __shared__ int s_olen[KK];
    __shared__ int s_src[64];

    // ---- Step 1: idx + olen for k = wave ----
    int idx;
    if (ttypes[b] == 20) {
        idx = (k == 0) ? 1 : 0;   // start_template: row0 -> one-hot(1), rest -> one-hot(0)
    } else {
        const int span = spans[b];
        float score = -INFINITY;
        int   bi    = 1000;
        if (lane < NP1) {
            const int base = (b * KK + k) * NP1 + lane;
            float logit = dec_logits[base];
            float u     = noise[base];
            float g     = -logf(-logf(u));            // gumbel noise
            float m     = (lane <= span) ? logit : -1e9f;
            score = m + g;
            bi    = lane;
        }
        // wave argmax, first-index tie-break (matches jnp.argmax)
        for (int off = 32; off; off >>= 1) {
            float s2 = __shfl_down(score, off);
            int   b2 = __shfl_down(bi, off);
            if (s2 > score || (s2 == score && b2 < bi)) { score = s2; bi = b2; }
        }
        idx = __shfl(bi, 0);
    }

    int olen = 0;
    if (idx > 0) {
        const float* base = decodings + (((size_t)b * NN + (idx - 1)) * MM) * (size_t)VV;
        for (int m = MM - 1; m >= 0; --m) {
            const f32x4* row = (const f32x4*)(base + (size_t)m * VV);
            f32x4 a = row[lane];        // v = 4*lane .. 4*lane+3
            f32x4 c = row[64 + lane];   // v = 256+4*lane .. +3
            float r0 = __shfl(a.x, 0);  // row[0]
            float mx = fmaxf(fmaxf(a.y, a.z), a.w);
            if (lane != 0) mx = fmaxf(mx, a.x);      // exclude v=0 only on lane 0
            mx = fmaxf(mx, fmaxf(fmaxf(c.x, c.y), fmaxf(c.z, c.w)));
            for (int off = 32; off; off >>= 1) mx = fmaxf(mx, __shfl_xor(mx, off));
            if (mx > r0) { olen = m + 1; break; }    // argmax(row) != 0
        }
    }

    if (lane == 0) {
        s_idx[k]  = idx;
        s_olen[k] = olen;
    }
    __syncthreads();

    // ---- Step 2: build row -> source map for our 64 rows ----
    if (tid < 64) {
        const int m_out = part * 64 + tid;
        int start = 0;
        int src   = -1;
        #pragma unroll
        for (int kk = 0; kk < KK; ++kk) {
            int id = s_idx[kk];
            int ol = min(s_olen[kk], MM - start);    // clip to remaining space
            if (m_out >= start && m_out < start + ol)
                src = (id - 1) * MM + (m_out - start);
            start += ol;
        }
        s_src[tid] = src;
    }
    __syncthreads();

    // ---- Step 3: gather 64 rows x 512 floats (8192 float4, 512 threads) ----
    // 16-deep: issue all loads first, then all stores.
    const f32x4* dec4 = (const f32x4*)(decodings + (size_t)b * NN * MM * VV);
    f32x4*       out4 = (f32x4*)(out + ((size_t)b * MM + part * 64) * (size_t)VV);

    f32x4 v[16];
    #pragma unroll
    for (int i = 0; i < 16; ++i) {
        int flat = i * 512 + tid;      // float4 index within our 64 rows
        int s    = s_src[flat >> 7];   // 128 float4 per row
        int v4   = flat & 127;
        v[i] = (s >= 0) ? dec4[(size_t)s * 128 + v4] : (f32x4){0.f, 0.f, 0.f, 0.f};
    }
    #pragma unroll
    for (int i = 0; i < 16; ++i) {
        out4[i * 512 + tid] = v[i];
    }
}

extern "C" void kernel_launch(void* const* d_in, const int* in_sizes, int n_in,
                              void* d_out, int out_size, void* d_ws, size_t ws_size,
                              hipStream_t stream) {
    const float* decodings  = (const float*)d_in[0];
    const float* dec_logits = (const float*)d_in[1];
    const float* noise      = (const float*)d_in[2];
    const int*   ttypes     = (const int*)d_in[3];
    const int*   spans      = (const int*)d_in[4];
    float* out = (float*)d_out;

    // 2 blocks per batch -> 512 blocks of 512 threads
    fused_place<<<BB * 2, 512, 0, stream>>>(decodings, dec_logits, noise,
                                            ttypes, spans, out);
}